// Round 16
// baseline (129.573 us; speedup 1.0000x reference)
//
#include <hip/hip_runtime.h>

typedef __bf16 bf16;
typedef __bf16 bf16x4 __attribute__((ext_vector_type(4)));
typedef __bf16 bf16x8 __attribute__((ext_vector_type(8)));
typedef float  f32x4  __attribute__((ext_vector_type(4)));

#define MFMA16(a, b, c) __builtin_amdgcn_mfma_f32_16x16x32_bf16((a), (b), (c), 0, 0, 0)

// R16 = R15 (67.1us best: pass1 deleted, s2 by sumMu-MFMA, zero barriers,
// 16.9KB LDS) with LEAN s2-frag construction to kill R15's residual spill:
//  * R15 arch-live audit: consts 72 + p00..p11 16 + h0/l0/h1/l1 16 + bs0/bs1 8
//    + s2q 16 + addr ~6 = ~138 > 128 -> VGPR pinned 128, 11MB scratch WRITE.
//  * Fix: build bs0 from (p00,p01) elementwise (per-element hi/lo/zero select),
//    retire temps, then bs1 from (p10,p11). Peak transients 40 -> 16,
//    worst-case live ~114 < 128. Identical math -> absmax 524288 unchanged.
// LAUNCH-BOUNDS RULE (R2/R4/R8): never min-waves>2. SPILL TRIPWIRE (R9/R12/R13/R15):
// VGPR pinned 128 + FETCH>>2.5MB or WRITE>>2KB => next trim: recompute xk/apk/bnk
// per-iter via shfl (-18 persistent regs).
__global__ __launch_bounds__(64, 2)
void qnet_kernel(const float* __restrict__ Xg, const float* __restrict__ Wg,
                 const float* __restrict__ W1g, const float* __restrict__ W2g,
                 const float* __restrict__ W3g, const float* __restrict__ W4g,
                 const float* __restrict__ W5g, const float* __restrict__ W6g,
                 const float* __restrict__ W7g, float* __restrict__ Outg)
{
    __shared__ __align__(16) bf16 muS[128 * 64];   // 16384 B, packed + swizzled
    __shared__ __align__(16) float uS[64];         // 256 B
    __shared__ __align__(16) float smS[64];        // 256 B  sumMu broadcast

    const int lane = threadIdx.x;       // 0..63, one wave
    const int b    = blockIdx.x;
    const int l15  = lane & 15;
    const int quad = lane >> 4;
    const int sw   = l15 & 7;           // swizzle key: k&7 == l15&7 for k=16kt+l15

    // ---------------- per-batch vectors (registers only) ----------------
    float xv0 = Xg[b * 128 + lane], xv1 = Xg[b * 128 + 64 + lane];
    float wv0 = Wg[b * 128 + lane], wv1 = Wg[b * 128 + 64 + lane];

    float Ap = fmaxf(wv0, 0.f) + fmaxf(wv1, 0.f);
    float Bn = fmaxf(-wv0, 0.f) + fmaxf(-wv1, 0.f);
#pragma unroll
    for (int m = 1; m < 64; m <<= 1) { Ap += __shfl_xor(Ap, m); Bn += __shfl_xor(Bn, m); }

    // per-kt scalars via shfl (k = kt*16 + l15)
    float xk[8], apk[8], bnk[8];
#pragma unroll
    for (int kt = 0; kt < 8; ++kt) {
        const int src = (kt & 3) * 16 + l15;
        float xs_ = (kt < 4) ? __shfl(xv0, src) : __shfl(xv1, src);
        float ws_ = (kt < 4) ? __shfl(wv0, src) : __shfl(wv1, src);
        xk[kt]  = xs_;
        apk[kt] = Ap - fmaxf(ws_, 0.f);
        bnk[kt] = Bn - fmaxf(-ws_, 0.f);
    }

    // v3p/v3m at q=lane (exact fp32), distribute to (qt,e) epilogue layout
    float sp = 0.f, sm = 0.f;
#pragma unroll
    for (int c = 0; c < 16; ++c) {
        f32x4 w4 = *(const f32x4*)&W4g[c * 4];
        f32x4 w3 = *(const f32x4*)&W3g[lane * 64 + c * 4];
#pragma unroll
        for (int e = 0; e < 4; ++e) {
            sp += fmaxf(w4[e], 0.f) * w3[e];
            sm += fmaxf(-w4[e], 0.f) * w3[e];
        }
    }
    float w1C[16], v3pC[16], v3mC[16];
#pragma unroll
    for (int qt = 0; qt < 4; ++qt) {
        f32x4 w1v = *(const f32x4*)&W1g[qt * 16 + quad * 4];
#pragma unroll
        for (int e = 0; e < 4; ++e) {
            const int q = qt * 16 + quad * 4 + e;
            v3pC[qt * 4 + e] = __shfl(sp, q);
            v3mC[qt * 4 + e] = __shfl(sm, q);
            w1C[qt * 4 + e]  = w1v[e];
        }
    }

    // u[p=lane] = W5b @ W7[:,p] -> uS (wave-private LDS)
    {
        float u = 0.f;
#pragma unroll
        for (int c = 0; c < 16; ++c) {
            f32x4 w5v = *(const f32x4*)&W5g[64 + c * 4];
#pragma unroll
            for (int e = 0; e < 4; ++e) u += w5v[e] * W7g[(c * 4 + e) * 64 + lane];
        }
        uS[lane] = u;
    }

    // W2 A-fragments (bf16 hi only)
    bf16x8 w2h[4][2];
#pragma unroll
    for (int qt = 0; qt < 4; ++qt)
#pragma unroll
        for (int s = 0; s < 2; ++s) {
            const float* src = &W2g[(qt * 16 + l15) * 64 + s * 32 + quad * 8];
            f32x4 f0 = *(const f32x4*)src;
            f32x4 f1 = *(const f32x4*)(src + 4);
            bf16x8 h;
#pragma unroll
            for (int e = 0; e < 4; ++e) { h[e] = (bf16)f0[e]; h[4 + e] = (bf16)f1[e]; }
            w2h[qt][s] = h;
        }

    // ---------------- mu1 = relu(base), exact fp32; accumulate smv ----------------
    float smv[16];
#pragma unroll
    for (int i = 0; i < 16; ++i) smv[i] = 0.f;
#pragma unroll
    for (int kt = 0; kt < 8; ++kt) {
        const int row = (kt * 16 + l15) * 64;
#pragma unroll
        for (int qt = 0; qt < 4; ++qt) {
            bf16x4 h;
#pragma unroll
            for (int e = 0; e < 4; ++e) {
                float t = fmaf(xk[kt], w1C[qt * 4 + e],
                          fmaf(apk[kt], v3pC[qt * 4 + e], bnk[kt] * v3mC[qt * 4 + e]));
                float v = fmaxf(t, 0.f);
                smv[qt * 4 + e] += v;
                h[e] = (bf16)v;
            }
            *(bf16x4*)&muS[row + ((2 * qt + (quad >> 1)) ^ sw) * 8 + 4 * (quad & 1)] = h;
        }
    }

    // ---------------- 3 iterations, zero barriers ----------------
    const f32x4 zero4 = {0.f, 0.f, 0.f, 0.f};
    for (int it = 0; it < 3; ++it) {
        // sumMu: l15 butterfly + publish to smS
#pragma unroll
        for (int m = 1; m <= 8; m <<= 1)
#pragma unroll
            for (int i = 0; i < 16; ++i) smv[i] += __shfl_xor(smv[i], m);
        if (l15 == 0) {
#pragma unroll
            for (int qt = 0; qt < 4; ++qt) {
                f32x4 v = {smv[qt * 4], smv[qt * 4 + 1], smv[qt * 4 + 2], smv[qt * 4 + 3]};
                *(f32x4*)&smS[qt * 16 + quad * 4] = v;
            }
        }
        // s2 = W2·sumMu by MFMA (R13/R15-verified math), LEAN frag build:
        // bs0 from (p00,p01) then retire; bs1 from (p10,p11). Sh in col n=0,
        // Sl in col n=1, zero elsewhere.
        bf16x8 bs0, bs1;
        {
            f32x4 pA = *(const f32x4*)&smS[quad * 8];
            f32x4 pB = *(const f32x4*)&smS[quad * 8 + 4];
#pragma unroll
            for (int e = 0; e < 4; ++e) {
                bf16 h = (bf16)pA[e];
                bs0[e] = (l15 == 0) ? h : ((l15 == 1) ? (bf16)(pA[e] - (float)h) : (bf16)0.f);
                bf16 g = (bf16)pB[e];
                bs0[4 + e] = (l15 == 0) ? g : ((l15 == 1) ? (bf16)(pB[e] - (float)g) : (bf16)0.f);
            }
            pA = *(const f32x4*)&smS[32 + quad * 8];
            pB = *(const f32x4*)&smS[32 + quad * 8 + 4];
#pragma unroll
            for (int e = 0; e < 4; ++e) {
                bf16 h = (bf16)pA[e];
                bs1[e] = (l15 == 0) ? h : ((l15 == 1) ? (bf16)(pA[e] - (float)h) : (bf16)0.f);
                bf16 g = (bf16)pB[e];
                bs1[4 + e] = (l15 == 0) ? g : ((l15 == 1) ? (bf16)(pB[e] - (float)g) : (bf16)0.f);
            }
        }
        f32x4 s2q[4];
#pragma unroll
        for (int qt = 0; qt < 4; ++qt) {
            f32x4 a = MFMA16(w2h[qt][0], bs0, zero4);
            a = MFMA16(w2h[qt][1], bs1, a);
#pragma unroll
            for (int e = 0; e < 4; ++e)
                s2q[qt][e] = __shfl(a[e], quad * 16) + __shfl(a[e], quad * 16 + 1);
        }

        // main pass: 64 MFMAs + fused epilogue (base recomputed fp32-exact)
#pragma unroll
        for (int i = 0; i < 16; ++i) smv[i] = 0.f;
#pragma unroll
        for (int kt = 0; kt < 8; ++kt) {
            const int row = (kt * 16 + l15) * 64;
            bf16x8 m0 = *(const bf16x8*)&muS[row + ((quad) ^ sw) * 8];
            bf16x8 m1 = *(const bf16x8*)&muS[row + ((4 + quad) ^ sw) * 8];
#pragma unroll
            for (int qt = 0; qt < 4; ++qt) {
                f32x4 a = MFMA16(w2h[qt][0], m0, zero4);
                a = MFMA16(w2h[qt][1], m1, a);
                bf16x4 h;
#pragma unroll
                for (int e = 0; e < 4; ++e) {
                    float t = fmaf(xk[kt], w1C[qt * 4 + e], s2q[qt][e]);
                    t = fmaf(apk[kt], v3pC[qt * 4 + e], t);
                    t = fmaf(bnk[kt], v3mC[qt * 4 + e], t);
                    float v = fmaxf(t - a[e], 0.f);
                    smv[qt * 4 + e] += v;
                    h[e] = (bf16)v;
                }
                *(bf16x4*)&muS[row + ((2 * qt + (quad >> 1)) ^ sw) * 8 + 4 * (quad & 1)] = h;
            }
        }
    }

    // ---------------- readout (wave-internal) ----------------
#pragma unroll
    for (int m = 1; m <= 8; m <<= 1)
#pragma unroll
        for (int i = 0; i < 16; ++i) smv[i] += __shfl_xor(smv[i], m);
    if (l15 == 0) {
#pragma unroll
        for (int qt = 0; qt < 4; ++qt) {
            f32x4 v = {smv[qt * 4], smv[qt * 4 + 1], smv[qt * 4 + 2], smv[qt * 4 + 3]};
            *(f32x4*)&smS[qt * 16 + quad * 4] = v;
        }
    }

    float pl = 0.f;
#pragma unroll
    for (int c = 0; c < 16; ++c) {
        f32x4 sv = *(const f32x4*)&smS[c * 4];
        f32x4 w6 = *(const f32x4*)&W6g[lane * 64 + c * 4];
#pragma unroll
        for (int e = 0; e < 4; ++e) pl = fmaf(sv[e], w6[e], pl);
    }
    float qa = fmaxf(pl, 0.f) * W5g[lane];
#pragma unroll
    for (int m = 1; m < 64; m <<= 1) qa += __shfl_xor(qa, m);

    f32x4 uf[2][2];
#pragma unroll
    for (int s = 0; s < 2; ++s) {
        uf[s][0] = *(const f32x4*)&uS[s * 32 + quad * 8];
        uf[s][1] = *(const f32x4*)&uS[s * 32 + quad * 8 + 4];
    }

    float res[8];
#pragma unroll
    for (int kt = 0; kt < 8; ++kt) {
        const int row = (kt * 16 + l15) * 64;
        bf16x8 m0 = *(const bf16x8*)&muS[row + ((quad) ^ sw) * 8];
        bf16x8 m1 = *(const bf16x8*)&muS[row + ((4 + quad) ^ sw) * 8];
        float r = 0.f;
#pragma unroll
        for (int j = 0; j < 4; ++j) {
            r = fmaf((float)m0[j],     uf[0][0][j], r);
            r = fmaf((float)m0[4 + j], uf[0][1][j], r);
            r = fmaf((float)m1[j],     uf[1][0][j], r);
            r = fmaf((float)m1[4 + j], uf[1][1][j], r);
        }
        r += __shfl_xor(r, 16); r += __shfl_xor(r, 32);
        res[kt] = r;
    }
    float rA0 = (quad & 1) ? res[1] : res[0];
    float rA1 = (quad & 1) ? res[3] : res[2];
    float rA  = (quad & 2) ? rA1 : rA0;
    float rB0 = (quad & 1) ? res[5] : res[4];
    float rB1 = (quad & 1) ? res[7] : res[6];
    float rB  = (quad & 2) ? rB1 : rB0;
    Outg[b * 128 + lane]      = qa + rA;   // k = lane       (kt = quad)
    Outg[b * 128 + 64 + lane] = qa + rB;   // k = lane + 64  (kt = quad + 4)
}

extern "C" void kernel_launch(void* const* d_in, const int* in_sizes, int n_in,
                              void* d_out, int out_size, void* d_ws, size_t ws_size,
                              hipStream_t stream) {
    (void)n_in; (void)d_ws; (void)ws_size; (void)out_size;
    const int B = in_sizes[0] >> 7;   // 4096
    qnet_kernel<<<B, 64, 0, stream>>>(
        (const float*)d_in[0], (const float*)d_in[1], (const float*)d_in[2],
        (const float*)d_in[3], (const float*)d_in[4], (const float*)d_in[5],
        (const float*)d_in[6], (const float*)d_in[7], (const float*)d_in[8],
        (float*)d_out);
}

// Round 17
// 125.844 us; speedup vs baseline: 1.0296x; 1.0296x over previous
//
#include <hip/hip_runtime.h>

typedef __bf16 bf16;
typedef __bf16 bf16x4 __attribute__((ext_vector_type(4)));
typedef __bf16 bf16x8 __attribute__((ext_vector_type(8)));
typedef float  f32x4  __attribute__((ext_vector_type(4)));

#define MFMA16(a, b, c) __builtin_amdgcn_mfma_f32_16x16x32_bf16((a), (b), (c), 0, 0, 0)

// R17 = R16 (s2-by-MFMA, pass1 deleted, zero barriers, 16.9KB LDS) with the
// xk/apk/bnk PERSISTENT ARRAYS DELETED (-24 -> +6 regs):
//  * recomputed per-kt inline from xv0/xv1/wv0/wv1/Ap/Bn via 2 shfls + 3 VALU
//    (unrolled loop -> kt<4 static). ~56 extra ops/iter, overlapped with MFMA.
//  * R15/R16 spill autopsy: at (64,2) unified budget 256 = arch 128 + acc 128;
//    loop arch-live was ~138 -> pinned 128 + 11MB scratch. New peak ~104 < 128.
//  * Math byte-identical to R16 -> absmax 524288.
// NEXT TRIM if still pinned: w1C/v3pC/v3mC (48 regs) -> wave-private LDS.
// LAUNCH-BOUNDS RULE (R2/R4/R8): never min-waves>2.
__global__ __launch_bounds__(64, 2)
void qnet_kernel(const float* __restrict__ Xg, const float* __restrict__ Wg,
                 const float* __restrict__ W1g, const float* __restrict__ W2g,
                 const float* __restrict__ W3g, const float* __restrict__ W4g,
                 const float* __restrict__ W5g, const float* __restrict__ W6g,
                 const float* __restrict__ W7g, float* __restrict__ Outg)
{
    __shared__ __align__(16) bf16 muS[128 * 64];   // 16384 B, packed + swizzled
    __shared__ __align__(16) float uS[64];         // 256 B
    __shared__ __align__(16) float smS[64];        // 256 B  sumMu broadcast

    const int lane = threadIdx.x;       // 0..63, one wave
    const int b    = blockIdx.x;
    const int l15  = lane & 15;
    const int quad = lane >> 4;
    const int sw   = l15 & 7;           // swizzle key: k&7 == l15&7 for k=16kt+l15

    // ---------------- per-batch vectors (6 persistent regs) ----------------
    float xv0 = Xg[b * 128 + lane], xv1 = Xg[b * 128 + 64 + lane];
    float wv0 = Wg[b * 128 + lane], wv1 = Wg[b * 128 + 64 + lane];

    float Ap = fmaxf(wv0, 0.f) + fmaxf(wv1, 0.f);
    float Bn = fmaxf(-wv0, 0.f) + fmaxf(-wv1, 0.f);
#pragma unroll
    for (int m = 1; m < 64; m <<= 1) { Ap += __shfl_xor(Ap, m); Bn += __shfl_xor(Bn, m); }

    // v3p/v3m at q=lane (exact fp32), distribute to (qt,e) epilogue layout
    float sp = 0.f, sm = 0.f;
#pragma unroll
    for (int c = 0; c < 16; ++c) {
        f32x4 w4 = *(const f32x4*)&W4g[c * 4];
        f32x4 w3 = *(const f32x4*)&W3g[lane * 64 + c * 4];
#pragma unroll
        for (int e = 0; e < 4; ++e) {
            sp += fmaxf(w4[e], 0.f) * w3[e];
            sm += fmaxf(-w4[e], 0.f) * w3[e];
        }
    }
    float w1C[16], v3pC[16], v3mC[16];
#pragma unroll
    for (int qt = 0; qt < 4; ++qt) {
        f32x4 w1v = *(const f32x4*)&W1g[qt * 16 + quad * 4];
#pragma unroll
        for (int e = 0; e < 4; ++e) {
            const int q = qt * 16 + quad * 4 + e;
            v3pC[qt * 4 + e] = __shfl(sp, q);
            v3mC[qt * 4 + e] = __shfl(sm, q);
            w1C[qt * 4 + e]  = w1v[e];
        }
    }

    // u[p=lane] = W5b @ W7[:,p] -> uS (wave-private LDS)
    {
        float u = 0.f;
#pragma unroll
        for (int c = 0; c < 16; ++c) {
            f32x4 w5v = *(const f32x4*)&W5g[64 + c * 4];
#pragma unroll
            for (int e = 0; e < 4; ++e) u += w5v[e] * W7g[(c * 4 + e) * 64 + lane];
        }
        uS[lane] = u;
    }

    // W2 A-fragments (bf16 hi only)
    bf16x8 w2h[4][2];
#pragma unroll
    for (int qt = 0; qt < 4; ++qt)
#pragma unroll
        for (int s = 0; s < 2; ++s) {
            const float* src = &W2g[(qt * 16 + l15) * 64 + s * 32 + quad * 8];
            f32x4 f0 = *(const f32x4*)src;
            f32x4 f1 = *(const f32x4*)(src + 4);
            bf16x8 h;
#pragma unroll
            for (int e = 0; e < 4; ++e) { h[e] = (bf16)f0[e]; h[4 + e] = (bf16)f1[e]; }
            w2h[qt][s] = h;
        }

    // ---------------- mu1 = relu(base), exact fp32; accumulate smv ----------------
    float smv[16];
#pragma unroll
    for (int i = 0; i < 16; ++i) smv[i] = 0.f;
#pragma unroll
    for (int kt = 0; kt < 8; ++kt) {
        const int src = (kt & 3) * 16 + l15;
        float xs_ = __shfl((kt < 4) ? xv0 : xv1, src);
        float ws_ = __shfl((kt < 4) ? wv0 : wv1, src);
        float ap_ = Ap - fmaxf(ws_, 0.f);
        float bn_ = Bn - fmaxf(-ws_, 0.f);
        const int row = (kt * 16 + l15) * 64;
#pragma unroll
        for (int qt = 0; qt < 4; ++qt) {
            bf16x4 h;
#pragma unroll
            for (int e = 0; e < 4; ++e) {
                float t = fmaf(xs_, w1C[qt * 4 + e],
                          fmaf(ap_, v3pC[qt * 4 + e], bn_ * v3mC[qt * 4 + e]));
                float v = fmaxf(t, 0.f);
                smv[qt * 4 + e] += v;
                h[e] = (bf16)v;
            }
            *(bf16x4*)&muS[row + ((2 * qt + (quad >> 1)) ^ sw) * 8 + 4 * (quad & 1)] = h;
        }
    }

    // ---------------- 3 iterations, zero barriers ----------------
    const f32x4 zero4 = {0.f, 0.f, 0.f, 0.f};
    for (int it = 0; it < 3; ++it) {
        // sumMu: l15 butterfly + publish to smS
#pragma unroll
        for (int m = 1; m <= 8; m <<= 1)
#pragma unroll
            for (int i = 0; i < 16; ++i) smv[i] += __shfl_xor(smv[i], m);
        if (l15 == 0) {
#pragma unroll
            for (int qt = 0; qt < 4; ++qt) {
                f32x4 v = {smv[qt * 4], smv[qt * 4 + 1], smv[qt * 4 + 2], smv[qt * 4 + 3]};
                *(f32x4*)&smS[qt * 16 + quad * 4] = v;
            }
        }
        // s2 = W2·sumMu by MFMA: lean frag build (Sh col 0, Sl col 1)
        bf16x8 bs0, bs1;
        {
            f32x4 pA = *(const f32x4*)&smS[quad * 8];
            f32x4 pB = *(const f32x4*)&smS[quad * 8 + 4];
#pragma unroll
            for (int e = 0; e < 4; ++e) {
                bf16 h = (bf16)pA[e];
                bs0[e] = (l15 == 0) ? h : ((l15 == 1) ? (bf16)(pA[e] - (float)h) : (bf16)0.f);
                bf16 g = (bf16)pB[e];
                bs0[4 + e] = (l15 == 0) ? g : ((l15 == 1) ? (bf16)(pB[e] - (float)g) : (bf16)0.f);
            }
            pA = *(const f32x4*)&smS[32 + quad * 8];
            pB = *(const f32x4*)&smS[32 + quad * 8 + 4];
#pragma unroll
            for (int e = 0; e < 4; ++e) {
                bf16 h = (bf16)pA[e];
                bs1[e] = (l15 == 0) ? h : ((l15 == 1) ? (bf16)(pA[e] - (float)h) : (bf16)0.f);
                bf16 g = (bf16)pB[e];
                bs1[4 + e] = (l15 == 0) ? g : ((l15 == 1) ? (bf16)(pB[e] - (float)g) : (bf16)0.f);
            }
        }
        f32x4 s2q[4];
#pragma unroll
        for (int qt = 0; qt < 4; ++qt) {
            f32x4 a = MFMA16(w2h[qt][0], bs0, zero4);
            a = MFMA16(w2h[qt][1], bs1, a);
#pragma unroll
            for (int e = 0; e < 4; ++e)
                s2q[qt][e] = __shfl(a[e], quad * 16) + __shfl(a[e], quad * 16 + 1);
        }

        // main pass: 64 MFMAs + fused epilogue (base recomputed fp32-exact,
        // per-kt scalars recomputed via shfl -- no persistent arrays)
#pragma unroll
        for (int i = 0; i < 16; ++i) smv[i] = 0.f;
#pragma unroll
        for (int kt = 0; kt < 8; ++kt) {
            const int src = (kt & 3) * 16 + l15;
            float xs_ = __shfl((kt < 4) ? xv0 : xv1, src);
            float ws_ = __shfl((kt < 4) ? wv0 : wv1, src);
            float ap_ = Ap - fmaxf(ws_, 0.f);
            float bn_ = Bn - fmaxf(-ws_, 0.f);
            const int row = (kt * 16 + l15) * 64;
            bf16x8 m0 = *(const bf16x8*)&muS[row + ((quad) ^ sw) * 8];
            bf16x8 m1 = *(const bf16x8*)&muS[row + ((4 + quad) ^ sw) * 8];
#pragma unroll
            for (int qt = 0; qt < 4; ++qt) {
                f32x4 a = MFMA16(w2h[qt][0], m0, zero4);
                a = MFMA16(w2h[qt][1], m1, a);
                bf16x4 h;
#pragma unroll
                for (int e = 0; e < 4; ++e) {
                    float t = fmaf(xs_, w1C[qt * 4 + e], s2q[qt][e]);
                    t = fmaf(ap_, v3pC[qt * 4 + e], t);
                    t = fmaf(bn_, v3mC[qt * 4 + e], t);
                    float v = fmaxf(t - a[e], 0.f);
                    smv[qt * 4 + e] += v;
                    h[e] = (bf16)v;
                }
                *(bf16x4*)&muS[row + ((2 * qt + (quad >> 1)) ^ sw) * 8 + 4 * (quad & 1)] = h;
            }
        }
    }

    // ---------------- readout (wave-internal) ----------------
#pragma unroll
    for (int m = 1; m <= 8; m <<= 1)
#pragma unroll
        for (int i = 0; i < 16; ++i) smv[i] += __shfl_xor(smv[i], m);
    if (l15 == 0) {
#pragma unroll
        for (int qt = 0; qt < 4; ++qt) {
            f32x4 v = {smv[qt * 4], smv[qt * 4 + 1], smv[qt * 4 + 2], smv[qt * 4 + 3]};
            *(f32x4*)&smS[qt * 16 + quad * 4] = v;
        }
    }

    float pl = 0.f;
#pragma unroll
    for (int c = 0; c < 16; ++c) {
        f32x4 sv = *(const f32x4*)&smS[c * 4];
        f32x4 w6 = *(const f32x4*)&W6g[lane * 64 + c * 4];
#pragma unroll
        for (int e = 0; e < 4; ++e) pl = fmaf(sv[e], w6[e], pl);
    }
    float qa = fmaxf(pl, 0.f) * W5g[lane];
#pragma unroll
    for (int m = 1; m < 64; m <<= 1) qa += __shfl_xor(qa, m);

    f32x4 uf[2][2];
#pragma unroll
    for (int s = 0; s < 2; ++s) {
        uf[s][0] = *(const f32x4*)&uS[s * 32 + quad * 8];
        uf[s][1] = *(const f32x4*)&uS[s * 32 + quad * 8 + 4];
    }

    float res[8];
#pragma unroll
    for (int kt = 0; kt < 8; ++kt) {
        const int row = (kt * 16 + l15) * 64;
        bf16x8 m0 = *(const bf16x8*)&muS[row + ((quad) ^ sw) * 8];
        bf16x8 m1 = *(const bf16x8*)&muS[row + ((4 + quad) ^ sw) * 8];
        float r = 0.f;
#pragma unroll
        for (int j = 0; j < 4; ++j) {
            r = fmaf((float)m0[j],     uf[0][0][j], r);
            r = fmaf((float)m0[4 + j], uf[0][1][j], r);
            r = fmaf((float)m1[j],     uf[1][0][j], r);
            r = fmaf((float)m1[4 + j], uf[1][1][j], r);
        }
        r += __shfl_xor(r, 16); r += __shfl_xor(r, 32);
        res[kt] = r;
    }
    float rA0 = (quad & 1) ? res[1] : res[0];
    float rA1 = (quad & 1) ? res[3] : res[2];
    float rA  = (quad & 2) ? rA1 : rA0;
    float rB0 = (quad & 1) ? res[5] : res[4];
    float rB1 = (quad & 1) ? res[7] : res[6];
    float rB  = (quad & 2) ? rB1 : rB0;
    Outg[b * 128 + lane]      = qa + rA;   // k = lane       (kt = quad)
    Outg[b * 128 + 64 + lane] = qa + rB;   // k = lane + 64  (kt = quad + 4)
}

extern "C" void kernel_launch(void* const* d_in, const int* in_sizes, int n_in,
                              void* d_out, int out_size, void* d_ws, size_t ws_size,
                              hipStream_t stream) {
    (void)n_in; (void)d_ws; (void)ws_size; (void)out_size;
    const int B = in_sizes[0] >> 7;   // 4096
    qnet_kernel<<<B, 64, 0, stream>>>(
        (const float*)d_in[0], (const float*)d_in[1], (const float*)d_in[2],
        (const float*)d_in[3], (const float*)d_in[4], (const float*)d_in[5],
        (const float*)d_in[6], (const float*)d_in[7], (const float*)d_in[8],
        (float*)d_out);
}